// Round 1
// baseline (232.383 us; speedup 1.0000x reference)
//
#include <hip/hip_runtime.h>
#include <hip/hip_bf16.h>

// Problem constants (from reference): VOCAB=1e6, DIM=64, BAGS=16384,
// N_IDX=819200, CAT_DIM=128. Output row = [eb(64) | eb(64) | cat(128)] = 256 f32.

__global__ __launch_bounds__(256) void quant_embag_kernel(
    const int* __restrict__ wq,            // [VOCAB, 64] int32 codes 0..15
    const float* __restrict__ scales,      // [VOCAB]
    const float* __restrict__ biases,      // [VOCAB]
    const unsigned int* __restrict__ idx32,// indices buffer viewed as u32
    const unsigned int* __restrict__ off32,// offsets buffer viewed as u32
    const float* __restrict__ cat,         // [BAGS, 128]
    float* __restrict__ out,               // [BAGS, 256]
    int num_bags)
{
    // Detect int64 vs int32 buffer layout for indices/offsets.
    // int64 (LE): high words of first 4 indices are all zero.
    // int32: those words are 4 random values in [0, 1e6) -> never all zero.
    const bool is64 = ((idx32[1] | idx32[3] | idx32[5] | idx32[7]) == 0u);
    const int sh = is64 ? 1 : 0;   // low 32 bits of element k live at word k<<sh

    const int wave = threadIdx.x >> 6;
    const int lane = threadIdx.x & 63;
    const int b = (blockIdx.x << 2) + wave;   // one wave per bag
    if (b >= num_bags) return;

    const int start = (int)off32[(unsigned)b << sh];
    const int end   = (int)off32[(unsigned)(b + 1) << sh];

    float accq = 0.0f;   // sum q*scale
    float accb = 0.0f;   // sum bias (same for every lane/dim of a row)
    for (int i = start; i < end; ++i) {
        const int idx = (int)idx32[(unsigned)i << sh];    // < 1e6, fits int32
        const float s  = scales[idx];
        const float bi = biases[idx];
        const int q = wq[idx * 64 + lane];                // coalesced 256B/wave
        accq = fmaf((float)q, s, accq);
        accb += bi;
    }
    const float acc = accq + accb;

    float* orow = out + (long long)b * 256;
    orow[lane]       = acc;                   // eb1
    orow[64 + lane]  = acc;                   // eb2 (identical computation)
    orow[128 + lane] = cat[(b << 7) + lane];  // cat copy
    orow[192 + lane] = cat[(b << 7) + 64 + lane];
}

extern "C" void kernel_launch(void* const* d_in, const int* in_sizes, int n_in,
                              void* d_out, int out_size, void* d_ws, size_t ws_size,
                              hipStream_t stream) {
    const int*          wq     = (const int*)d_in[0];
    const float*        scales = (const float*)d_in[1];
    const float*        biases = (const float*)d_in[2];
    const unsigned int* idx32  = (const unsigned int*)d_in[3];
    const unsigned int* off32  = (const unsigned int*)d_in[4];
    const float*        cat    = (const float*)d_in[5];
    float*              out    = (float*)d_out;

    const int num_bags = in_sizes[5] / 128;          // 16384
    const int grid = (num_bags + 3) / 4;             // 4 bags (waves) per block

    quant_embag_kernel<<<grid, 256, 0, stream>>>(
        wq, scales, biases, idx32, off32, cat, out, num_bags);
}

// Round 2
// 75.478 us; speedup vs baseline: 3.0788x; 3.0788x over previous
//
#include <hip/hip_runtime.h>

// VOCAB=1e6, DIM=64, BAGS=16384, N_IDX=819200, CAT_DIM=128.
// Output row = [eb(64) | eb(64) | cat(128)] = 256 f32.
// Strategy: index-parallel. 819200 / 100 = 8192 chunks = exactly one chunk per
// wave at full occupancy (2048 blocks x 4 waves), perfect load balance.
// Per-bag partial sums accumulated in registers, flushed with atomicAdd at
// bag boundaries (~3 segments/wave).

constexpr int CHUNK = 100;

__global__ __launch_bounds__(256) void init_out_kernel(
    const float* __restrict__ cat, float* __restrict__ out, int total)
{
    int t = blockIdx.x * 256 + threadIdx.x;   // total = num_bags*256
    if (t >= total) return;
    int b = t >> 8, c = t & 255;
    out[t] = (c < 128) ? 0.0f : cat[(b << 7) + (c - 128)];
}

__global__ __launch_bounds__(256) void embag_atomic_kernel(
    const int* __restrict__ wq,             // [VOCAB, 64] int32 codes
    const float* __restrict__ scales,       // [VOCAB]
    const float* __restrict__ biases,       // [VOCAB]
    const unsigned int* __restrict__ idx32, // indices viewed as u32 words
    const unsigned int* __restrict__ off32, // offsets viewed as u32 words
    float* __restrict__ out,                // [BAGS, 256]
    int num_bags, int n_idx)
{
    // int64 vs int32 layout detection (LE): high words of first indices == 0.
    const bool is64 = ((idx32[1] | idx32[3] | idx32[5] | idx32[7]) == 0u);
    const int sh = is64 ? 1 : 0;

    const int lane = threadIdx.x & 63;
    const int wid  = blockIdx.x * 4 + (threadIdx.x >> 6);
    const int i0   = wid * CHUNK;
    if (i0 >= n_idx) return;
    const int i1 = min(i0 + CHUNK, n_idx);

    // smallest b with off[b+1] > i0  (== largest b with off[b] <= i0,
    // matching searchsorted-right semantics incl. duplicate offsets)
    int lo = 0, hi = num_bags - 1;
    while (lo < hi) {
        int mid = (lo + hi) >> 1;
        int v = (int)off32[(unsigned)(mid + 1) << sh];
        if (v > i0) hi = mid; else lo = mid + 1;
    }
    int b = lo;
    int i = i0;

    while (i < i1) {
        const int bend = (int)off32[(unsigned)(b + 1) << sh];
        const int e = min(bend, i1);
        if (e > i) {
            float accq = 0.0f, accb = 0.0f;
            #pragma unroll 4
            for (int j = i; j < e; ++j) {
                const int idx = (int)idx32[(unsigned)j << sh]; // broadcast load
                const float s  = scales[idx];
                const float bi = biases[idx];
                const int q = wq[idx * 64 + lane];             // 256B/wave gather
                accq = fmaf((float)q, s, accq);
                accb += bi;
            }
            const float acc = accq + accb;
            float* p = out + ((long long)b << 8) + lane;
            atomicAdd(p, acc);        // eb1
            atomicAdd(p + 64, acc);   // eb2 (identical sum)
            i = e;
        }
        if (bend <= i1) ++b; else break;   // advance past (possibly empty) bags
    }
}

extern "C" void kernel_launch(void* const* d_in, const int* in_sizes, int n_in,
                              void* d_out, int out_size, void* d_ws, size_t ws_size,
                              hipStream_t stream) {
    const int*          wq     = (const int*)d_in[0];
    const float*        scales = (const float*)d_in[1];
    const float*        biases = (const float*)d_in[2];
    const unsigned int* idx32  = (const unsigned int*)d_in[3];
    const unsigned int* off32  = (const unsigned int*)d_in[4];
    const float*        cat    = (const float*)d_in[5];
    float*              out    = (float*)d_out;

    const int num_bags = in_sizes[5] / 128;       // 16384
    const int n_idx    = in_sizes[3];             // 819200

    const int total = num_bags * 256;
    init_out_kernel<<<(total + 255) / 256, 256, 0, stream>>>(cat, out, total);

    const int nchunks = (n_idx + CHUNK - 1) / CHUNK;   // 8192
    const int blocks  = (nchunks + 3) / 4;             // 2048
    embag_atomic_kernel<<<blocks, 256, 0, stream>>>(
        wq, scales, biases, idx32, off32, out, num_bags, n_idx);
}